// Round 4
// baseline (1325.075 us; speedup 1.0000x reference)
//
#include <hip/hip_runtime.h>

#define Bb 8
#define HDc 1024
#define MR 8192  // L*B rows

typedef __attribute__((ext_vector_type(8))) short bf16x8;
typedef __attribute__((ext_vector_type(4))) float f32x4;

__device__ __forceinline__ float bf2f(unsigned short u){
  union { unsigned int i; float f; } x; x.i = ((unsigned int)u) << 16; return x.f;
}
__device__ __forceinline__ unsigned short f2bf(float f){
  union { float f; unsigned int i; } x; x.f = f;
  unsigned int r = x.i + 0x7fffu + ((x.i >> 16) & 1u);
  return (unsigned short)(r >> 16);
}

// ---------------- fp32 -> bf16 convert ----------------
__global__ void k_f2bf(const float* __restrict__ src, unsigned short* __restrict__ dst, int n){
  int i = (blockIdx.x * blockDim.x + threadIdx.x) * 4;
  int stride = gridDim.x * blockDim.x * 4;
  for (; i < n; i += stride){
    const float4 v = *(const float4*)(src + i);
    uint2 o;
    o.x = (unsigned int)f2bf(v.x) | ((unsigned int)f2bf(v.y) << 16);
    o.y = (unsigned int)f2bf(v.z) | ((unsigned int)f2bf(v.w) << 16);
    *(uint2*)(dst + i) = o;
  }
}

// ---------------- W (k,n) fp32 -> Wt (n,k) bf16, 1024x1024 ----------------
__global__ void k_wtrans(const float* __restrict__ W, unsigned short* __restrict__ Wt){
  __shared__ float t[32][33];
  int bx = blockIdx.x, by = blockIdx.y;
  int tx = threadIdx.x, ty = threadIdx.y;
  #pragma unroll
  for (int i = 0; i < 32; i += 8)
    t[ty + i][tx] = W[(size_t)(by*32 + ty + i)*1024 + bx*32 + tx];
  __syncthreads();
  #pragma unroll
  for (int i = 0; i < 32; i += 8)
    Wt[(size_t)(bx*32 + ty + i)*1024 + by*32 + tx] = f2bf(t[tx][ty + i]);
}

// ---------------- vp (n*B+b, HD) bf16 -> vT[b][c][n] bf16 ----------------
__global__ void k_vtrans(const unsigned short* __restrict__ vp, unsigned short* __restrict__ vT){
  __shared__ unsigned short t[32][33];
  int ct = blockIdx.x, nt = blockIdx.y, b = blockIdx.z;
  int tx = threadIdx.x, ty = threadIdx.y;
  #pragma unroll
  for (int i = 0; i < 32; i += 8)
    t[ty + i][tx] = vp[((size_t)(nt*32 + ty + i)*Bb + b)*HDc + ct*32 + tx];
  __syncthreads();
  #pragma unroll
  for (int i = 0; i < 32; i += 8)
    vT[((size_t)b*1024 + ct*32 + ty + i)*1024 + nt*32 + tx] = t[tx][ty + i];
}

// ---------------- bf16 GEMM: A(M,K) row-major, Bt(N,K) row-major, C = A@Bt^T + bias
// M=8192, N=K=1024. OUTF=0 -> bf16 C, OUTF=1 -> fp32 C.
template<int OUTF>
__global__ __launch_bounds__(256) void k_gemm(const unsigned short* __restrict__ A,
                                              const unsigned short* __restrict__ Bt,
                                              const float* __restrict__ bias,
                                              void* __restrict__ C){
  const int K = 1024;
  __shared__ unsigned short As[128][72];  // +8 pad: conflict-free ds_read_b128
  __shared__ unsigned short Bs[128][72];
  const int m0 = blockIdx.y * 128, n0 = blockIdx.x * 128;
  const int tid = threadIdx.x;
  const int w = tid >> 6, l = tid & 63, l15 = l & 15, qrt = l >> 4;
  const int wi = w >> 1, wj = w & 1;
  f32x4 acc[4][4] = {};
  for (int k0 = 0; k0 < K; k0 += 64){
    __syncthreads();
    #pragma unroll
    for (int i = 0; i < 4; ++i){
      int c = i*256 + tid;
      int r = c >> 3, cb = (c & 7) * 8;
      *(bf16x8*)&As[r][cb] = *(const bf16x8*)&A[(size_t)(m0 + r)*K + k0 + cb];
      *(bf16x8*)&Bs[r][cb] = *(const bf16x8*)&Bt[(size_t)(n0 + r)*K + k0 + cb];
    }
    __syncthreads();
    #pragma unroll
    for (int kk = 0; kk < 2; ++kk){
      bf16x8 af[4], bfr[4];
      #pragma unroll
      for (int f = 0; f < 4; ++f){
        af[f]  = *(const bf16x8*)&As[wi*64 + f*16 + l15][kk*32 + qrt*8];
        bfr[f] = *(const bf16x8*)&Bs[wj*64 + f*16 + l15][kk*32 + qrt*8];
      }
      #pragma unroll
      for (int fi = 0; fi < 4; ++fi)
        #pragma unroll
        for (int fj = 0; fj < 4; ++fj)
          acc[fi][fj] = __builtin_amdgcn_mfma_f32_16x16x32_bf16(af[fi], bfr[fj], acc[fi][fj], 0, 0, 0);
    }
  }
  #pragma unroll
  for (int fj = 0; fj < 4; ++fj){
    int n = n0 + wj*64 + fj*16 + l15;
    float bv = bias[n];
    #pragma unroll
    for (int fi = 0; fi < 4; ++fi){
      int mb = m0 + wi*64 + fi*16 + qrt*4;
      #pragma unroll
      for (int r = 0; r < 4; ++r){
        float v = acc[fi][fj][r] + bv;
        if (OUTF) ((float*)C)[(size_t)(mb + r)*1024 + n] = v;
        else ((unsigned short*)C)[(size_t)(mb + r)*1024 + n] = f2bf(v);
      }
    }
  }
}

// ---------------- fused attention ----------------
// grid (32 i-tiles, 8 b), block 1024 (16 waves).
// Per block: rows i0..i0+31, loop h: S=QK^T (MFMA), softmax+mask+renorm, P->LDS(bf16,
// XOR-swizzled), PV (MFMA, 2-way j-split + LDS pair reduce) -> ctx bf16.
// attn.mean accumulated in registers across h, written once.
__global__ __launch_bounds__(1024) void k_attn(
    const unsigned short* __restrict__ qp,
    const unsigned short* __restrict__ kp,
    const unsigned short* __restrict__ vT,
    const float* __restrict__ mask,
    unsigned short* __restrict__ ctx,
    float* __restrict__ attn_mean)
{
  __shared__ unsigned short Qlds[32][64];                 // 4 KB
  __shared__ __align__(16) unsigned char Plds[32*1024*2]; // 64 KB, swizzled
  __shared__ float redM[16][16];
  __shared__ float redA[16][16];
  __shared__ float redB[16][16];
  __shared__ float rowM[32];
  __shared__ float rowD[32];
  __shared__ float redPV[8][16][16];                      // 8 KB

  const int b  = blockIdx.y;
  const int i0 = blockIdx.x * 32;
  const int tid = threadIdx.x;
  const int w = tid >> 6;
  const int l = tid & 63;
  const int l15 = l & 15;
  const int qrt = l >> 4;
  const int it = w & 1;        // S-phase i-tile (16 rows)
  const int slice = w >> 1;    // S-phase j-slice (8 slices x 128 cols)
  const int dt  = (w >> 1) & 3; // PV d-tile
  const int jh  = w >> 3;       // PV j-half

  float accM[8][4];
  #pragma unroll
  for (int q = 0; q < 8; ++q)
    #pragma unroll
    for (int r = 0; r < 4; ++r) accM[q][r] = 0.f;

  for (int h = 0; h < 16; ++h) {
    // ---- stage Q (pre-scaled by 1/8 = D^-0.5, exact in bf16) ----
    {
      int e = tid * 2;
      int r = e >> 6, c = e & 63;
      unsigned int v = *(const unsigned int*)&qp[((size_t)(i0 + r)*Bb + b)*HDc + h*64 + c];
      float f0 = bf2f((unsigned short)(v & 0xffff)) * 0.125f;
      float f1 = bf2f((unsigned short)(v >> 16)) * 0.125f;
      *(unsigned int*)&Qlds[r][c] = (unsigned int)f2bf(f0) | ((unsigned int)f2bf(f1) << 16);
    }
    __syncthreads();

    bf16x8 qa0 = *(const bf16x8*)&Qlds[it*16 + l15][qrt*8];
    bf16x8 qa1 = *(const bf16x8*)&Qlds[it*16 + l15][32 + qrt*8];

    // ---- S = (Q*scale) K^T ----
    f32x4 p[8];
    #pragma unroll
    for (int q = 0; q < 8; ++q) {
      int j = (slice*8 + q)*16 + l15;
      const unsigned short* kr = &kp[((size_t)j*Bb + b)*HDc + h*64 + qrt*8];
      bf16x8 kb0 = *(const bf16x8*)kr;
      bf16x8 kb1 = *(const bf16x8*)(kr + 32);
      f32x4 a = {0.f, 0.f, 0.f, 0.f};
      a = __builtin_amdgcn_mfma_f32_16x16x32_bf16(qa0, kb0, a, 0, 0, 0);
      a = __builtin_amdgcn_mfma_f32_16x16x32_bf16(qa1, kb1, a, 0, 0, 0);
      p[q] = a;
    }

    // ---- row max (in-lane -> 16-lane shfl -> cross-wave via LDS) ----
    float pm[4];
    #pragma unroll
    for (int r = 0; r < 4; ++r) {
      float m = p[0][r];
      #pragma unroll
      for (int q = 1; q < 8; ++q) m = fmaxf(m, p[q][r]);
      #pragma unroll
      for (int d = 1; d < 16; d <<= 1) m = fmaxf(m, __shfl_xor(m, d, 16));
      pm[r] = m;
    }
    if (l15 == 0) {
      #pragma unroll
      for (int r = 0; r < 4; ++r) redM[w][qrt*4 + r] = pm[r];
    }
    __syncthreads();
    if (tid < 32) {
      int half = tid >> 4, ridx = tid & 15;
      float m = redM[half][ridx];
      #pragma unroll
      for (int s = 1; s < 8; ++s) m = fmaxf(m, redM[2*s + half][ridx]);
      rowM[tid] = m;
    }
    __syncthreads();

    // ---- exp, mask, partial sums ----
    float mrow[4];
    #pragma unroll
    for (int r = 0; r < 4; ++r) mrow[r] = rowM[it*16 + qrt*4 + r];
    float se[4] = {0,0,0,0}, sm[4] = {0,0,0,0};
    #pragma unroll
    for (int q = 0; q < 8; ++q) {
      int j = (slice*8 + q)*16 + l15;
      #pragma unroll
      for (int r = 0; r < 4; ++r) {
        int row = i0 + it*16 + qrt*4 + r;
        float mk = mask[(((size_t)(b*16 + h))*1024 + row)*1024 + j];
        float e = exp2f((p[q][r] - mrow[r]) * 1.44269504f);
        float pe = e * mk;
        se[r] += e; sm[r] += pe;
        p[q][r] = pe;
      }
    }
    #pragma unroll
    for (int r = 0; r < 4; ++r) {
      #pragma unroll
      for (int d = 1; d < 16; d <<= 1) {
        se[r] += __shfl_xor(se[r], d, 16);
        sm[r] += __shfl_xor(sm[r], d, 16);
      }
    }
    if (l15 == 0) {
      #pragma unroll
      for (int r = 0; r < 4; ++r) { redA[w][qrt*4 + r] = se[r]; redB[w][qrt*4 + r] = sm[r]; }
    }
    __syncthreads();
    if (tid < 32) {
      int half = tid >> 4, ridx = tid & 15;
      float te = 0.f, tm = 0.f;
      #pragma unroll
      for (int s = 0; s < 8; ++s) { te += redA[2*s + half][ridx]; tm += redB[2*s + half][ridx]; }
      rowD[tid] = 1.0f / (tm + 1e-4f * te);  // attn = e*mask / (Sem + 1e-4*Se)
    }
    __syncthreads();

    // ---- attn values: mean-acc + P write (swizzled bf16) ----
    float dr[4];
    #pragma unroll
    for (int r = 0; r < 4; ++r) dr[r] = rowD[it*16 + qrt*4 + r];
    #pragma unroll
    for (int q = 0; q < 8; ++q) {
      int j = (slice*8 + q)*16 + l15;
      #pragma unroll
      for (int r = 0; r < 4; ++r) {
        int row = it*16 + qrt*4 + r;
        float a = p[q][r] * dr[r];
        accM[q][r] += a;
        int byte = (row*2048 + j*2) ^ ((row & 7) << 4);
        *(unsigned short*)(Plds + byte) = f2bf(a);
      }
    }
    __syncthreads();

    // ---- PV: O = P @ V, j split across 2 wave-halves ----
    f32x4 o = {0.f, 0.f, 0.f, 0.f};
    #pragma unroll
    for (int st = 0; st < 16; ++st) {
      int j0 = jh*512 + st*32 + qrt*8;
      int prow = it*16 + l15;
      int pbyte = (prow*2048 + j0*2) ^ ((prow & 7) << 4);
      bf16x8 pa = *(const bf16x8*)(Plds + pbyte);
      bf16x8 vb = *(const bf16x8*)&vT[((size_t)b*1024 + h*64 + dt*16 + l15)*1024 + j0];
      o = __builtin_amdgcn_mfma_f32_16x16x32_bf16(pa, vb, o, 0, 0, 0);
    }
    if (jh == 1) {
      #pragma unroll
      for (int r = 0; r < 4; ++r) redPV[w - 8][qrt*4 + r][l15] = o[r];
    }
    __syncthreads();
    if (jh == 0) {
      #pragma unroll
      for (int r = 0; r < 4; ++r) {
        float val = o[r] + redPV[w][qrt*4 + r][l15];
        int row = i0 + it*16 + qrt*4 + r;
        ctx[((size_t)row*Bb + b)*HDc + h*64 + dt*16 + l15] = f2bf(val);
      }
    }
    __syncthreads();
  }

  // ---- write attn.mean over heads: (B, L, N) fp32 ----
  #pragma unroll
  for (int q = 0; q < 8; ++q) {
    int j = (slice*8 + q)*16 + l15;
    #pragma unroll
    for (int r = 0; r < 4; ++r) {
      int row = i0 + it*16 + qrt*4 + r;
      attn_mean[((size_t)b*1024 + row)*1024 + j] = accM[q][r] * 0.0625f;
    }
  }
}

extern "C" void kernel_launch(void* const* d_in, const int* in_sizes, int n_in,
                              void* d_out, int out_size, void* d_ws, size_t ws_size,
                              hipStream_t stream)
{
  const float* q    = (const float*)d_in[0];
  const float* k    = (const float*)d_in[1];
  const float* v    = (const float*)d_in[2];
  const float* mask = (const float*)d_in[3];
  const float* Wq   = (const float*)d_in[4];
  const float* bq   = (const float*)d_in[5];
  const float* Wk   = (const float*)d_in[6];
  const float* bk   = (const float*)d_in[7];
  const float* Wv   = (const float*)d_in[8];
  const float* bv   = (const float*)d_in[9];
  const float* Wout = (const float*)d_in[10];
  const float* bout = (const float*)d_in[11];

  char* ws = (char*)d_ws;
  const size_t MB16 = 16u*1024u*1024u;
  unsigned short* xq  = (unsigned short*)(ws + 0*MB16);
  unsigned short* xk  = (unsigned short*)(ws + 1*MB16);
  unsigned short* xv  = (unsigned short*)(ws + 2*MB16);
  unsigned short* qp  = (unsigned short*)(ws + 3*MB16);
  unsigned short* kp  = (unsigned short*)(ws + 4*MB16);
  unsigned short* vp  = (unsigned short*)(ws + 5*MB16);
  unsigned short* wtq = (unsigned short*)(ws + 6*MB16);
  unsigned short* wtk = (unsigned short*)(ws + 6*MB16 + 2u*1024u*1024u);
  unsigned short* wtv = (unsigned short*)(ws + 6*MB16 + 4u*1024u*1024u);
  unsigned short* wto = (unsigned short*)(ws + 6*MB16 + 6u*1024u*1024u);
  unsigned short* vT  = xk;  // xk dead after kp GEMM
  unsigned short* ctx = xq;  // xq dead after qp GEMM
  float* out0 = (float*)d_out;
  float* out1 = out0 + (size_t)MR*1024;

  const int nElem = MR * 1024;
  k_f2bf<<<1024, 256, 0, stream>>>(q, xq, nElem);
  k_f2bf<<<1024, 256, 0, stream>>>(k, xk, nElem);
  k_f2bf<<<1024, 256, 0, stream>>>(v, xv, nElem);

  dim3 wb(32, 8);
  dim3 wg(32, 32);
  k_wtrans<<<wg, wb, 0, stream>>>(Wq, wtq);
  k_wtrans<<<wg, wb, 0, stream>>>(Wk, wtk);
  k_wtrans<<<wg, wb, 0, stream>>>(Wv, wtv);

  dim3 gg(8, 64);
  k_gemm<0><<<gg, 256, 0, stream>>>(xq, wtq, bq, (void*)qp);
  k_gemm<0><<<gg, 256, 0, stream>>>(xk, wtk, bk, (void*)kp);
  k_gemm<0><<<gg, 256, 0, stream>>>(xv, wtv, bv, (void*)vp);

  dim3 vg(32, 32, 8);
  k_vtrans<<<vg, wb, 0, stream>>>(vp, vT);

  dim3 ag(32, 8);
  k_attn<<<ag, 1024, 0, stream>>>(qp, kp, vT, mask, ctx, out1);

  k_wtrans<<<wg, wb, 0, stream>>>(Wout, wto);
  k_gemm<1><<<gg, 256, 0, stream>>>(ctx, wto, bout, (void*)out0);
}